// Round 1
// 79922.882 us; speedup vs baseline: 1.3606x; 1.3606x over previous
//
#include <hip/hip_runtime.h>
#include <hip/hip_bf16.h>
#include <math.h>

#define BB 256
#define TT 256
#define VV 33
#define HH 512
#define DD 256
#define KKEY 512
#define G4 2048
#define K1 832     // GEMM-K layer1: [a 0:256 | h 256:768 | x 768:801 | pad 801:832]
#define K1A 768    // xcat1 row stride (a+h only)
#define K1X 64     // packed-x row stride (33 data + zero pad), 128B rows (16B aligned)
#define K2 1280    // [hprev 0:512 | a 512:768 | hself 768:1280]

typedef unsigned short u16;
typedef unsigned int u32;
typedef __attribute__((ext_vector_type(8))) short short8;
typedef __attribute__((ext_vector_type(4))) float float4v;

__device__ inline float bf2f(u16 v) {
    union { u32 u; float f; } c; c.u = ((u32)v) << 16; return c.f;
}
__device__ inline u16 f2bf(float f) {
    __hip_bfloat16 h = __float2bfloat16(f);
    union { __hip_bfloat16 h; u16 u; } c; c.h = h; return c.u;
}
__device__ inline void split_bf(float v, u16& hi, u16& lo) {
    hi = f2bf(v);
    lo = f2bf(v - bf2f(hi));
}

// ---------------- weight prep: Wt[col'][k], gate-interleaved columns ----------------
// col' = u*4 + g  <->  original col = g*512 + u
__global__ void prep_v7(const float* __restrict__ W, const float* __restrict__ U,
                        u16* __restrict__ WtH, u16* __restrict__ WtL, int Kd, int mode) {
    long idx = (long)blockIdx.x * blockDim.x + threadIdx.x;
    if (idx >= (long)G4 * Kd) return;
    int colp = (int)(idx / Kd);
    int k = (int)(idx % Kd);
    int col = (colp & 3) * 512 + (colp >> 2);
    float v = 0.f;
    if (mode == 1) {
        // k-order: [a 0:256 -> W rows 33:289 | h 256:768 -> U | x 768:801 -> W rows 0:33]
        if (k < 256)      v = W[(long)(33 + k) * G4 + col];
        else if (k < 768) v = U[(long)(k - 256) * G4 + col];
        else if (k < 801) v = W[(long)(k - 768) * G4 + col];
    } else {
        // [hprev 0:512 | a 512:768] -> W rows 0:768 | hself 768:1280 -> U
        if (k < 768) v = W[(long)k * G4 + col];
        else         v = U[(long)(k - 768) * G4 + col];
    }
    u16 hi, lo; split_bf(v, hi, lo);
    WtH[idx] = hi; WtL[idx] = lo;
}

// ---------------- pre-pack x for ALL t: xP[t][b][64] (33 data, rest zero) ----------------
__global__ void packx_v7(const float* __restrict__ x, u16* __restrict__ xPH, u16* __restrict__ xPL) {
    long idx = (long)blockIdx.x * blockDim.x + threadIdx.x;
    if (idx >= (long)TT * BB * K1X) return;
    int k = (int)(idx % K1X);
    long tb = idx / K1X;
    int b = (int)(tb % BB);
    int t = (int)(tb / BB);
    float v = (k < VV) ? x[((long)b * TT + t) * VV + k] : 0.f;
    u16 hi, lo; split_bf(v, hi, lo);
    xPH[idx] = hi; xPL[idx] = lo;
}

// ---------------- fused z-GEMM + LSTM gates ----------------
// z[b][col'] = xcat[b][:] . Wt[col'][:]; then gates applied in-block (cols gate-interleaved),
// writes c, h (fp32) and h as bf16 hi/lo into up to two xcat destination slots.
__global__ __launch_bounds__(256) void zg_v7(
    const u16* __restrict__ aH, const u16* __restrict__ aL, int strideA, int Kd,
    const u16* __restrict__ xH, const u16* __restrict__ xL,   // layer1 x source (else null)
    const u16* __restrict__ wH, const u16* __restrict__ wL,
    const float* __restrict__ bias,
    float* __restrict__ c, float* __restrict__ h,
    u16* __restrict__ d0H, u16* __restrict__ d0L, int d0off, int d0stride,
    u16* __restrict__ d1H, u16* __restrict__ d1L, int d1off, int d1stride)
{
    __shared__ u16 AldsH[64 * 40];
    __shared__ u16 AldsL[64 * 40];
    __shared__ u16 WldsH[64 * 40];
    __shared__ u16 WldsL[64 * 40];
    __shared__ float zlds[64 * 68];

    int tid = threadIdx.x;
    int mt = blockIdx.x >> 5;    // 0..3
    int nt = blockIdx.x & 31;    // 0..31
    int M0 = mt * 64, N0 = nt * 64;

    int wave = tid >> 6, lane = tid & 63;
    int lr = lane & 15, lg = lane >> 4;
    int srow = tid >> 2, spart = tid & 3;

    const u16* aRowH = aH + (long)(M0 + srow) * strideA;
    const u16* aRowL = aL + (long)(M0 + srow) * strideA;
    const u16* xRowH = xH ? xH + (long)(M0 + srow) * K1X : nullptr;
    const u16* xRowL = xL ? xL + (long)(M0 + srow) * K1X : nullptr;
    const u16* wRowH = wH + (long)(N0 + srow) * Kd;
    const u16* wRowL = wL + (long)(N0 + srow) * Kd;

    float4v acc[4];
    #pragma unroll
    for (int i = 0; i < 4; i++) acc[i] = (float4v){0.f, 0.f, 0.f, 0.f};

    for (int k0 = 0; k0 < Kd; k0 += 32) {
        int kg = k0 + spart * 8;
        uint4 vaH, vaL;
        if (!xH || kg < K1A) {
            vaH = *(const uint4*)(aRowH + kg);
            vaL = *(const uint4*)(aRowL + kg);
        } else {
            vaH = *(const uint4*)(xRowH + (kg - K1A));
            vaL = *(const uint4*)(xRowL + (kg - K1A));
        }
        uint4 vwH = *(const uint4*)(wRowH + kg);
        uint4 vwL = *(const uint4*)(wRowL + kg);
        __syncthreads();
        *(uint4*)(&AldsH[srow * 40 + spart * 8]) = vaH;
        *(uint4*)(&AldsL[srow * 40 + spart * 8]) = vaL;
        *(uint4*)(&WldsH[srow * 40 + spart * 8]) = vwH;
        *(uint4*)(&WldsL[srow * 40 + spart * 8]) = vwL;
        __syncthreads();
        // A fragment: m = wave*16 + (lane&15), k = (lane>>4)*8 + j   [m120-verified]
        short8 ah = *(const short8*)(&AldsH[(wave * 16 + lr) * 40 + lg * 8]);
        short8 al = *(const short8*)(&AldsL[(wave * 16 + lr) * 40 + lg * 8]);
        #pragma unroll
        for (int tt = 0; tt < 4; tt++) {
            short8 bh = *(const short8*)(&WldsH[(tt * 16 + lr) * 40 + lg * 8]);
            short8 bl = *(const short8*)(&WldsL[(tt * 16 + lr) * 40 + lg * 8]);
            acc[tt] = __builtin_amdgcn_mfma_f32_16x16x32_bf16(ah, bh, acc[tt], 0, 0, 0);
            acc[tt] = __builtin_amdgcn_mfma_f32_16x16x32_bf16(ah, bl, acc[tt], 0, 0, 0);
            acc[tt] = __builtin_amdgcn_mfma_f32_16x16x32_bf16(al, bh, acc[tt], 0, 0, 0);
        }
    }

    // D: col = lane&15 (within 16-block), row m = (lane>>4)*4 + r   [m89-verified]
    #pragma unroll
    for (int tt = 0; tt < 4; tt++) {
        int lc = tt * 16 + lr;
        #pragma unroll
        for (int r = 0; r < 4; r++)
            zlds[(wave * 16 + lg * 4 + r) * 68 + lc] = acc[tt][r];
    }
    __syncthreads();

    // gates: thread (um, mm) handles u = U0+um over 4 rows
    int um = tid & 15, mm = tid >> 4;
    int u = (nt << 4) + um;
    float bi  = bias[u];
    float bf_ = bias[512 + u];
    float bg  = bias[1024 + u];
    float bo_ = bias[1536 + u];
    #pragma unroll
    for (int r = 0; r < 4; r++) {
        int ml = mm * 4 + r;
        int m = M0 + ml;
        float zi  = zlds[ml * 68 + um * 4 + 0] + bi;
        float zf  = zlds[ml * 68 + um * 4 + 1] + bf_;
        float zg_ = zlds[ml * 68 + um * 4 + 2] + bg;
        float zo  = zlds[ml * 68 + um * 4 + 3] + bo_;
        float i_ = 1.f / (1.f + expf(-zi));
        float f_ = 1.f / (1.f + expf(-zf));
        float g_ = tanhf(zg_);
        float o_ = 1.f / (1.f + expf(-zo));
        long idx = (long)m * HH + u;
        float cn = f_ * c[idx] + i_ * g_;
        c[idx] = cn;
        float hn = o_ * tanhf(cn);
        h[idx] = hn;
        u16 hi_, lo_; split_bf(hn, hi_, lo_);
        if (d0H) {
            d0H[(long)m * d0stride + d0off + u] = hi_;
            d0L[(long)m * d0stride + d0off + u] = lo_;
        }
        d1H[(long)m * d1stride + d1off + u] = hi_;
        d1L[(long)m * d1stride + d1off + u] = lo_;
    }
}

// ---------------- fused q = h@Wq+bq, attention, (layer3: + output projection) ----------------
__global__ __launch_bounds__(256) void qattn_v7(
    const float* __restrict__ h, const float* __restrict__ Wq,
    const float* __restrict__ bq, const float* __restrict__ keys,
    u16* __restrict__ dH, u16* __restrict__ dL, int doff, int dstride,
    const float* __restrict__ Wo, const float* __restrict__ bo,
    float* __restrict__ out, int t)
{
    __shared__ float hlds[HH];
    __shared__ float qlds[DD];
    __shared__ float plds[KKEY];
    __shared__ float alds[DD];
    __shared__ float red[8];

    int b = blockIdx.x, tid = threadIdx.x;
    int lane = tid & 63, wave = tid >> 6;

    hlds[tid]       = h[(long)b * HH + tid];
    hlds[tid + 256] = h[(long)b * HH + 256 + tid];
    __syncthreads();

    // q[d] for d = tid
    {
        float s = bq[tid];
        #pragma unroll 8
        for (int j = 0; j < HH; j++)
            s += hlds[j] * Wq[(long)j * DD + tid];
        qlds[tid] = s;
    }
    __syncthreads();

    const float* kb = keys + (long)b * KKEY * DD;

    // scores (2 key rows per thread)
    float s0 = 0.f, s1 = 0.f;
    const float* kr0 = kb + (long)tid * DD;
    const float* kr1 = kb + (long)(tid + 256) * DD;
    for (int d = 0; d < DD; d += 4) {
        float4 k0 = *(const float4*)(kr0 + d);
        float4 k1 = *(const float4*)(kr1 + d);
        float q0 = qlds[d], q1 = qlds[d + 1], q2 = qlds[d + 2], q3 = qlds[d + 3];
        s0 += k0.x * q0 + k0.y * q1 + k0.z * q2 + k0.w * q3;
        s1 += k1.x * q0 + k1.y * q1 + k1.z * q2 + k1.w * q3;
    }
    float m = fmaxf(s0, s1);
    for (int o = 32; o > 0; o >>= 1) m = fmaxf(m, __shfl_xor(m, o));
    if (lane == 0) red[wave] = m;
    __syncthreads();
    m = fmaxf(fmaxf(red[0], red[1]), fmaxf(red[2], red[3]));

    float p0 = expf(s0 - m), p1 = expf(s1 - m);
    plds[tid] = p0;
    plds[tid + 256] = p1;
    float ps = p0 + p1;
    for (int o = 32; o > 0; o >>= 1) ps += __shfl_xor(ps, o);
    if (lane == 0) red[4 + wave] = ps;
    __syncthreads();
    float l = red[4] + red[5] + red[6] + red[7];

    float acc = 0.f;
    for (int k = 0; k < KKEY; k++)
        acc += plds[k] * kb[(long)k * DD + tid];
    float av = acc / l;

    u16 hi_, lo_; split_bf(av, hi_, lo_);
    dH[(long)b * dstride + doff + tid] = hi_;
    dL[(long)b * dstride + doff + tid] = lo_;

    if (Wo) {
        alds[tid] = av;
        __syncthreads();
        // out[v] = bo[v] + h3 . Wo[0:512][v] + a3 . Wo[512:768][v]; wave-parallel over i
        for (int v = wave; v < VV; v += 4) {
            float s = 0.f;
            for (int i = lane; i < HH; i += 64) s += hlds[i] * Wo[(long)i * VV + v];
            for (int i = lane; i < DD; i += 64) s += alds[i] * Wo[(long)(HH + i) * VV + v];
            for (int o = 32; o > 0; o >>= 1) s += __shfl_xor(s, o);
            if (lane == 0) out[((long)b * TT + t) * VV + v] = s + bo[v];
        }
    }
}

// ---------------- launch ----------------

extern "C" void kernel_launch(void* const* d_in, const int* in_sizes, int n_in,
                              void* d_out, int out_size, void* d_ws, size_t ws_size,
                              hipStream_t stream) {
    const float *x = nullptr, *keys = nullptr, *W1 = nullptr, *U1 = nullptr,
                *b1 = nullptr, *W2 = nullptr, *U2 = nullptr, *b2 = nullptr,
                *W3 = nullptr, *U3 = nullptr, *b3 = nullptr, *Wq = nullptr,
                *bq = nullptr, *Wo = nullptr, *bo = nullptr;
    {
        int cW23 = 0, cU = 0, cb = 0;
        for (int i = 0; i < n_in; i++) {
            const float* q = (const float*)d_in[i];
            switch (in_sizes[i]) {
                case 2162688:  x = q; break;
                case 33554432: keys = q; break;
                case 591872:   W1 = q; break;
                case 1572864:  if (cW23 == 0) W2 = q; else W3 = q; cW23++; break;
                case 1048576:  if (cU == 0) U1 = q; else if (cU == 1) U2 = q; else U3 = q; cU++; break;
                case 2048:     if (cb == 0) b1 = q; else if (cb == 1) b2 = q; else b3 = q; cb++; break;
                case 131072:   Wq = q; break;
                case 256:      bq = q; break;
                case 25344:    Wo = q; break;
                case 33:       bo = q; break;
                default: break;
            }
        }
    }
    float* out = (float*)d_out;

    char* p = (char*)d_ws;
    auto alloc = [&](size_t n) { char* r = p; p += (n + 255) & ~(size_t)255; return r; };
    // weights (bf16 hi/lo, transposed [col'][k], gate-interleaved cols)
    u16* WtH1 = (u16*)alloc((size_t)G4 * K1 * 2);
    u16* WtL1 = (u16*)alloc((size_t)G4 * K1 * 2);
    u16* WtH2 = (u16*)alloc((size_t)G4 * K2 * 2);
    u16* WtL2 = (u16*)alloc((size_t)G4 * K2 * 2);
    u16* WtH3 = (u16*)alloc((size_t)G4 * K2 * 2);
    u16* WtL3 = (u16*)alloc((size_t)G4 * K2 * 2);
    // pre-packed x for all t
    u16* xPH = (u16*)alloc((size_t)TT * BB * K1X * 2);
    u16* xPL = (u16*)alloc((size_t)TT * BB * K1X * 2);
    // xcat staging (bf16 hi/lo), double-buffered by t-parity
    u16* xc1H[2]; u16* xc1L[2]; u16* xc2H[2]; u16* xc2L[2]; u16* xc3H[2]; u16* xc3L[2];
    for (int i = 0; i < 2; i++) {
        xc1H[i] = (u16*)alloc((size_t)BB * K1A * 2);
        xc1L[i] = (u16*)alloc((size_t)BB * K1A * 2);
        xc2H[i] = (u16*)alloc((size_t)BB * K2 * 2);
        xc2L[i] = (u16*)alloc((size_t)BB * K2 * 2);
        xc3H[i] = (u16*)alloc((size_t)BB * K2 * 2);
        xc3L[i] = (u16*)alloc((size_t)BB * K2 * 2);
    }
    // fp32 state
    float* h1 = (float*)alloc((size_t)BB * HH * 4);
    float* c1 = (float*)alloc((size_t)BB * HH * 4);
    float* h2 = (float*)alloc((size_t)BB * HH * 4);
    float* c2 = (float*)alloc((size_t)BB * HH * 4);
    float* h3 = (float*)alloc((size_t)BB * HH * 4);
    float* c3 = (float*)alloc((size_t)BB * HH * 4);

    // prep
    {
        long t1 = (long)G4 * K1;
        prep_v7<<<(int)((t1 + 255) / 256), 256, 0, stream>>>(W1, U1, WtH1, WtL1, K1, 1);
        long t2 = (long)G4 * K2;
        prep_v7<<<(int)((t2 + 255) / 256), 256, 0, stream>>>(W2, U2, WtH2, WtL2, K2, 2);
        prep_v7<<<(int)((t2 + 255) / 256), 256, 0, stream>>>(W3, U3, WtH3, WtL3, K2, 2);
        long tx = (long)TT * BB * K1X;
        packx_v7<<<(int)((tx + 255) / 256), 256, 0, stream>>>(x, xPH, xPL);
        hipMemsetAsync(c1, 0, (size_t)BB * HH * 4, stream);
        hipMemsetAsync(c2, 0, (size_t)BB * HH * 4, stream);
        hipMemsetAsync(c3, 0, (size_t)BB * HH * 4, stream);
        // t=0 inputs: a=0, h=0 in xcat buffers (parity 0)
        hipMemsetAsync(xc1H[0], 0, (size_t)BB * K1A * 2, stream);
        hipMemsetAsync(xc1L[0], 0, (size_t)BB * K1A * 2, stream);
        hipMemsetAsync(xc2H[0], 0, (size_t)BB * K2 * 2, stream);
        hipMemsetAsync(xc2L[0], 0, (size_t)BB * K2 * 2, stream);
        hipMemsetAsync(xc3H[0], 0, (size_t)BB * K2 * 2, stream);
        hipMemsetAsync(xc3L[0], 0, (size_t)BB * K2 * 2, stream);
    }

    for (int t = 0; t < TT; t++) {
        int cur = t & 1, nxt = cur ^ 1;
        // L1: z1 = [a3|h1|x_t] @ Wt1 -> gates -> h1; h1 bf16 -> xc2[cur] hprev, xc1[nxt] hself
        zg_v7<<<128, 256, 0, stream>>>(
            xc1H[cur], xc1L[cur], K1A, K1,
            xPH + (long)t * BB * K1X, xPL + (long)t * BB * K1X,
            WtH1, WtL1, b1, c1, h1,
            xc2H[cur], xc2L[cur], 0, K2,
            xc1H[nxt], xc1L[nxt], 256, K1A);
        // a1 -> xc2[cur] a-slot
        qattn_v7<<<BB, 256, 0, stream>>>(h1, Wq, bq, keys,
            xc2H[cur], xc2L[cur], 512, K2,
            nullptr, nullptr, nullptr, 0);
        // L2
        zg_v7<<<128, 256, 0, stream>>>(
            xc2H[cur], xc2L[cur], K2, K2, nullptr, nullptr,
            WtH2, WtL2, b2, c2, h2,
            xc3H[cur], xc3L[cur], 0, K2,
            xc2H[nxt], xc2L[nxt], 768, K2);
        qattn_v7<<<BB, 256, 0, stream>>>(h2, Wq, bq, keys,
            xc3H[cur], xc3L[cur], 512, K2,
            nullptr, nullptr, nullptr, 0);
        // L3 (no d0; h3 self-recurrence only)
        zg_v7<<<128, 256, 0, stream>>>(
            xc3H[cur], xc3L[cur], K2, K2, nullptr, nullptr,
            WtH3, WtL3, b3, c3, h3,
            nullptr, nullptr, 0, 0,
            xc3H[nxt], xc3L[nxt], 768, K2);
        // a3 -> xc1[nxt] a-slot; fused output projection
        qattn_v7<<<BB, 256, 0, stream>>>(h3, Wq, bq, keys,
            xc1H[nxt], xc1L[nxt], 0, K1A,
            Wo, bo, out, t);
    }
}

// Round 2
// 61202.765 us; speedup vs baseline: 1.7768x; 1.3059x over previous
//
#include <hip/hip_runtime.h>
#include <hip/hip_bf16.h>
#include <math.h>

#define BB 256
#define TT 256
#define VV 33
#define HH 512
#define DD 256
#define KKEY 512
#define G4 2048
#define K1 832     // GEMM-K layer1: [a 0:256 | h 256:768 | x 768:801 | pad 801:832]
#define K1A 768    // xcat1 row stride (a+h only)
#define K1X 64     // packed-x row stride (33 data + zero pad)
#define K2 1280    // [hprev 0:512 | a 512:768 | hself 768:1280]
#define CH 32      // attention keys chunk rows
#define KP 260     // klds row stride (fp32), 256 + 4 pad

typedef unsigned short u16;
typedef unsigned int u32;
typedef __attribute__((ext_vector_type(8))) short short8;
typedef __attribute__((ext_vector_type(4))) float float4v;

__device__ inline float bf2f(u16 v) {
    union { u32 u; float f; } c; c.u = ((u32)v) << 16; return c.f;
}
__device__ inline u16 f2bf(float f) {
    __hip_bfloat16 h = __float2bfloat16(f);
    union { __hip_bfloat16 h; u16 u; } c; c.h = h; return c.u;
}
__device__ inline void split_bf(float v, u16& hi, u16& lo) {
    hi = f2bf(v);
    lo = f2bf(v - bf2f(hi));
}

// ---------------- weight prep: Wt[col'][k], gate-interleaved columns ----------------
// col' = u*4 + g  <->  original col = g*512 + u
__global__ void prep_v7(const float* __restrict__ W, const float* __restrict__ U,
                        u16* __restrict__ WtH, u16* __restrict__ WtL, int Kd, int mode) {
    long idx = (long)blockIdx.x * blockDim.x + threadIdx.x;
    if (idx >= (long)G4 * Kd) return;
    int colp = (int)(idx / Kd);
    int k = (int)(idx % Kd);
    int col = (colp & 3) * 512 + (colp >> 2);
    float v = 0.f;
    if (mode == 1) {
        if (k < 256)      v = W[(long)(33 + k) * G4 + col];
        else if (k < 768) v = U[(long)(k - 256) * G4 + col];
        else if (k < 801) v = W[(long)(k - 768) * G4 + col];
    } else {
        if (k < 768) v = W[(long)k * G4 + col];
        else         v = U[(long)(k - 768) * G4 + col];
    }
    u16 hi, lo; split_bf(v, hi, lo);
    WtH[idx] = hi; WtL[idx] = lo;
}

// ---------------- pre-pack x for ALL t: xP[t][b][64] (33 data, rest zero) ----------------
__global__ void packx_v7(const float* __restrict__ x, u16* __restrict__ xPH, u16* __restrict__ xPL) {
    long idx = (long)blockIdx.x * blockDim.x + threadIdx.x;
    if (idx >= (long)TT * BB * K1X) return;
    int k = (int)(idx % K1X);
    long tb = idx / K1X;
    int b = (int)(tb % BB);
    int t = (int)(tb / BB);
    float v = (k < VV) ? x[((long)b * TT + t) * VV + k] : 0.f;
    u16 hi, lo; split_bf(v, hi, lo);
    xPH[idx] = hi; xPL[idx] = lo;
}

// ---------------- fused z-GEMM + LSTM gates; 32x32 tiles, grid 512 ----------------
__global__ __launch_bounds__(256, 2) void zg_v8(
    const u16* __restrict__ aH, const u16* __restrict__ aL, int strideA, int Kd,
    const u16* __restrict__ xH, const u16* __restrict__ xL,   // layer1 x source (else null)
    const u16* __restrict__ wH, const u16* __restrict__ wL,
    const float* __restrict__ bias,
    float* __restrict__ c, float* __restrict__ h,
    u16* __restrict__ d0H, u16* __restrict__ d0L, int d0off, int d0stride,
    u16* __restrict__ d1H, u16* __restrict__ d1L, int d1off, int d1stride)
{
    __shared__ u16 AldsH[32 * 40];
    __shared__ u16 AldsL[32 * 40];
    __shared__ u16 WldsH[32 * 40];
    __shared__ u16 WldsL[32 * 40];
    __shared__ float zlds[32 * 36];

    int tid = threadIdx.x;
    int mt = blockIdx.x >> 6;    // 0..7
    int nt = blockIdx.x & 63;    // 0..63
    int M0 = mt * 32, N0 = nt * 32;

    int wave = tid >> 6, lane = tid & 63;
    int lr = lane & 15, lg = lane >> 4;
    int rbase = (wave & 1) * 16, cbase = (wave >> 1) * 16;

    // staging: half picks H/L, slot picks (row 0..31, part 0..3); one A + one W load each
    int half = tid >> 7;
    int slot = tid & 127;
    int sr = slot >> 2, sp = slot & 3;

    const u16* aRow = (half ? aL : aH) + (long)(M0 + sr) * strideA;
    const u16* xRow = xH ? ((half ? xL : xH) + (long)(M0 + sr) * K1X) : nullptr;
    const u16* wRow = (half ? wL : wH) + (long)(N0 + sr) * Kd;
    u16* aDst = (half ? AldsL : AldsH) + sr * 40 + sp * 8;
    u16* wDst = (half ? WldsL : WldsH) + sr * 40 + sp * 8;

    float4v acc = (float4v){0.f, 0.f, 0.f, 0.f};

    for (int k0 = 0; k0 < Kd; k0 += 32) {
        int kg = k0 + sp * 8;
        uint4 va = (xRow && kg >= K1A) ? *(const uint4*)(xRow + (kg - K1A))
                                       : *(const uint4*)(aRow + kg);
        uint4 vw = *(const uint4*)(wRow + kg);
        __syncthreads();
        *(uint4*)aDst = va;
        *(uint4*)wDst = vw;
        __syncthreads();
        // A fragment: m = rbase + (lane&15), k = (lane>>4)*8 + j   [m120-verified]
        short8 ah = *(const short8*)(&AldsH[(rbase + lr) * 40 + lg * 8]);
        short8 al = *(const short8*)(&AldsL[(rbase + lr) * 40 + lg * 8]);
        short8 bh = *(const short8*)(&WldsH[(cbase + lr) * 40 + lg * 8]);
        short8 bl = *(const short8*)(&WldsL[(cbase + lr) * 40 + lg * 8]);
        acc = __builtin_amdgcn_mfma_f32_16x16x32_bf16(ah, bh, acc, 0, 0, 0);
        acc = __builtin_amdgcn_mfma_f32_16x16x32_bf16(ah, bl, acc, 0, 0, 0);
        acc = __builtin_amdgcn_mfma_f32_16x16x32_bf16(al, bh, acc, 0, 0, 0);
    }

    // D: col = lane&15, row = (lane>>4)*4 + r   [m89-verified]
    #pragma unroll
    for (int r = 0; r < 4; r++)
        zlds[(rbase + lg * 4 + r) * 36 + cbase + lr] = acc[r];
    __syncthreads();

    // gates: 1 row x 1 unit per thread
    int um = tid & 7, ml = tid >> 3;       // um 0..7, ml 0..31
    int u = (nt << 3) + um;
    int m = M0 + ml;
    float zi  = zlds[ml * 36 + um * 4 + 0] + bias[u];
    float zf  = zlds[ml * 36 + um * 4 + 1] + bias[512 + u];
    float zg_ = zlds[ml * 36 + um * 4 + 2] + bias[1024 + u];
    float zo  = zlds[ml * 36 + um * 4 + 3] + bias[1536 + u];
    float i_ = 1.f / (1.f + expf(-zi));
    float f_ = 1.f / (1.f + expf(-zf));
    float g_ = tanhf(zg_);
    float o_ = 1.f / (1.f + expf(-zo));
    long idx = (long)m * HH + u;
    float cn = f_ * c[idx] + i_ * g_;
    c[idx] = cn;
    float hn = o_ * tanhf(cn);
    h[idx] = hn;
    u16 hi_, lo_; split_bf(hn, hi_, lo_);
    if (d0H) {
        d0H[(long)m * d0stride + d0off + u] = hi_;
        d0L[(long)m * d0stride + d0off + u] = lo_;
    }
    d1H[(long)m * d1stride + d1off + u] = hi_;
    d1L[(long)m * d1stride + d1off + u] = lo_;
}

// ---------------- fused q + single-pass flash attention (+ layer3 output proj) ----------------
__global__ __launch_bounds__(256) void qattn_v8(
    const float* __restrict__ h, const float* __restrict__ Wq,
    const float* __restrict__ bq, const float* __restrict__ keys,
    u16* __restrict__ dH, u16* __restrict__ dL, int doff, int dstride,
    const float* __restrict__ Wo, const float* __restrict__ bo,
    float* __restrict__ out, int t)
{
    __shared__ __align__(16) float hlds[HH];
    __shared__ __align__(16) float qlds[DD];
    __shared__ __align__(16) float klds[CH * KP];
    __shared__ __align__(16) float slds[CH];
    __shared__ __align__(16) float plds[CH];
    __shared__ __align__(16) float alds[DD];

    int b = blockIdx.x, tid = threadIdx.x;
    int lane = tid & 63, wave = tid >> 6;

    hlds[tid]       = h[(long)b * HH + tid];
    hlds[tid + 256] = h[(long)b * HH + 256 + tid];
    __syncthreads();

    // q[d] for d = tid (4 partial accumulators for ILP)
    {
        float s0 = 0.f, s1 = 0.f, s2 = 0.f, s3 = 0.f;
        #pragma unroll 8
        for (int j = 0; j < HH; j += 4) {
            s0 += hlds[j]     * Wq[(long)j * DD + tid];
            s1 += hlds[j + 1] * Wq[(long)(j + 1) * DD + tid];
            s2 += hlds[j + 2] * Wq[(long)(j + 2) * DD + tid];
            s3 += hlds[j + 3] * Wq[(long)(j + 3) * DD + tid];
        }
        qlds[tid] = (s0 + s1) + (s2 + s3) + bq[tid];
    }
    __syncthreads();

    const float* kb = keys + (long)b * KKEY * DD;
    float4 q4 = *(const float4*)(&qlds[lane * 4]);

    float m_run = -INFINITY, l_run = 0.f, acc = 0.f;

    // prefetch chunk 0: thread covers rows wave+4i, dims lane*4..+4
    float4 kv[8];
    #pragma unroll
    for (int i = 0; i < 8; i++)
        kv[i] = *(const float4*)(kb + (long)(wave + 4 * i) * DD + lane * 4);

    for (int k0 = 0; k0 < KKEY; k0 += CH) {
        __syncthreads();   // klds WAR vs previous accumulation
        float pp[8];
        #pragma unroll
        for (int i = 0; i < 8; i++) {
            *(float4*)(&klds[(wave + 4 * i) * KP + lane * 4]) = kv[i];
            pp[i] = kv[i].x * q4.x + kv[i].y * q4.y + kv[i].z * q4.z + kv[i].w * q4.w;
        }
        // prefetch next chunk (overlaps with reduce + softmax + accumulate)
        float4 kn[8];
        if (k0 + CH < KKEY) {
            #pragma unroll
            for (int i = 0; i < 8; i++)
                kn[i] = *(const float4*)(kb + (long)(k0 + CH + wave + 4 * i) * DD + lane * 4);
        }
        // wave-wide reduce of partial dots -> scores
        #pragma unroll
        for (int i = 0; i < 8; i++) {
            float s = pp[i];
            s += __shfl_xor(s, 32); s += __shfl_xor(s, 16); s += __shfl_xor(s, 8);
            s += __shfl_xor(s, 4);  s += __shfl_xor(s, 2);  s += __shfl_xor(s, 1);
            if (lane == i) slds[wave + 4 * i] = s;
        }
        __syncthreads();
        // softmax bookkeeping (uniform)
        float mc = slds[0];
        #pragma unroll
        for (int k = 1; k < CH; k++) mc = fmaxf(mc, slds[k]);
        float m_new = fmaxf(m_run, mc);
        float scale = expf(m_run - m_new);
        if (tid < CH) plds[tid] = expf(slds[tid] - m_new);
        __syncthreads();
        // weighted accumulation: thread owns dim d = tid
        float lsum = 0.f, a0 = 0.f, a1 = 0.f;
        #pragma unroll
        for (int k = 0; k < CH; k += 4) {
            float4 p4 = *(const float4*)(&plds[k]);
            lsum += (p4.x + p4.y) + (p4.z + p4.w);
            a0 += p4.x * klds[(k + 0) * KP + tid] + p4.z * klds[(k + 2) * KP + tid];
            a1 += p4.y * klds[(k + 1) * KP + tid] + p4.w * klds[(k + 3) * KP + tid];
        }
        acc = acc * scale + (a0 + a1);
        l_run = l_run * scale + lsum;
        m_run = m_new;
        #pragma unroll
        for (int i = 0; i < 8; i++) kv[i] = kn[i];
    }

    float av = acc / l_run;
    u16 hi_, lo_; split_bf(av, hi_, lo_);
    dH[(long)b * dstride + doff + tid] = hi_;
    dL[(long)b * dstride + doff + tid] = lo_;

    if (Wo) {
        alds[tid] = av;
        __syncthreads();
        for (int v = wave; v < VV; v += 4) {
            float s = 0.f;
            for (int i = lane; i < HH; i += 64) s += hlds[i] * Wo[(long)i * VV + v];
            for (int i = lane; i < DD; i += 64) s += alds[i] * Wo[(long)(HH + i) * VV + v];
            for (int o = 32; o > 0; o >>= 1) s += __shfl_xor(s, o);
            if (lane == 0) out[((long)b * TT + t) * VV + v] = s + bo[v];
        }
    }
}

// ---------------- launch ----------------

extern "C" void kernel_launch(void* const* d_in, const int* in_sizes, int n_in,
                              void* d_out, int out_size, void* d_ws, size_t ws_size,
                              hipStream_t stream) {
    const float *x = nullptr, *keys = nullptr, *W1 = nullptr, *U1 = nullptr,
                *b1 = nullptr, *W2 = nullptr, *U2 = nullptr, *b2 = nullptr,
                *W3 = nullptr, *U3 = nullptr, *b3 = nullptr, *Wq = nullptr,
                *bq = nullptr, *Wo = nullptr, *bo = nullptr;
    {
        int cW23 = 0, cU = 0, cb = 0;
        for (int i = 0; i < n_in; i++) {
            const float* q = (const float*)d_in[i];
            switch (in_sizes[i]) {
                case 2162688:  x = q; break;
                case 33554432: keys = q; break;
                case 591872:   W1 = q; break;
                case 1572864:  if (cW23 == 0) W2 = q; else W3 = q; cW23++; break;
                case 1048576:  if (cU == 0) U1 = q; else if (cU == 1) U2 = q; else U3 = q; cU++; break;
                case 2048:     if (cb == 0) b1 = q; else if (cb == 1) b2 = q; else b3 = q; cb++; break;
                case 131072:   Wq = q; break;
                case 256:      bq = q; break;
                case 25344:    Wo = q; break;
                case 33:       bo = q; break;
                default: break;
            }
        }
    }
    float* out = (float*)d_out;

    char* p = (char*)d_ws;
    auto alloc = [&](size_t n) { char* r = p; p += (n + 255) & ~(size_t)255; return r; };
    u16* WtH1 = (u16*)alloc((size_t)G4 * K1 * 2);
    u16* WtL1 = (u16*)alloc((size_t)G4 * K1 * 2);
    u16* WtH2 = (u16*)alloc((size_t)G4 * K2 * 2);
    u16* WtL2 = (u16*)alloc((size_t)G4 * K2 * 2);
    u16* WtH3 = (u16*)alloc((size_t)G4 * K2 * 2);
    u16* WtL3 = (u16*)alloc((size_t)G4 * K2 * 2);
    u16* xPH = (u16*)alloc((size_t)TT * BB * K1X * 2);
    u16* xPL = (u16*)alloc((size_t)TT * BB * K1X * 2);
    u16* xc1H[2]; u16* xc1L[2]; u16* xc2H[2]; u16* xc2L[2]; u16* xc3H[2]; u16* xc3L[2];
    for (int i = 0; i < 2; i++) {
        xc1H[i] = (u16*)alloc((size_t)BB * K1A * 2);
        xc1L[i] = (u16*)alloc((size_t)BB * K1A * 2);
        xc2H[i] = (u16*)alloc((size_t)BB * K2 * 2);
        xc2L[i] = (u16*)alloc((size_t)BB * K2 * 2);
        xc3H[i] = (u16*)alloc((size_t)BB * K2 * 2);
        xc3L[i] = (u16*)alloc((size_t)BB * K2 * 2);
    }
    float* h1 = (float*)alloc((size_t)BB * HH * 4);
    float* c1 = (float*)alloc((size_t)BB * HH * 4);
    float* h2 = (float*)alloc((size_t)BB * HH * 4);
    float* c2 = (float*)alloc((size_t)BB * HH * 4);
    float* h3 = (float*)alloc((size_t)BB * HH * 4);
    float* c3 = (float*)alloc((size_t)BB * HH * 4);

    {
        long t1 = (long)G4 * K1;
        prep_v7<<<(int)((t1 + 255) / 256), 256, 0, stream>>>(W1, U1, WtH1, WtL1, K1, 1);
        long t2 = (long)G4 * K2;
        prep_v7<<<(int)((t2 + 255) / 256), 256, 0, stream>>>(W2, U2, WtH2, WtL2, K2, 2);
        prep_v7<<<(int)((t2 + 255) / 256), 256, 0, stream>>>(W3, U3, WtH3, WtL3, K2, 2);
        long tx = (long)TT * BB * K1X;
        packx_v7<<<(int)((tx + 255) / 256), 256, 0, stream>>>(x, xPH, xPL);
        hipMemsetAsync(c1, 0, (size_t)BB * HH * 4, stream);
        hipMemsetAsync(c2, 0, (size_t)BB * HH * 4, stream);
        hipMemsetAsync(c3, 0, (size_t)BB * HH * 4, stream);
        hipMemsetAsync(xc1H[0], 0, (size_t)BB * K1A * 2, stream);
        hipMemsetAsync(xc1L[0], 0, (size_t)BB * K1A * 2, stream);
        hipMemsetAsync(xc2H[0], 0, (size_t)BB * K2 * 2, stream);
        hipMemsetAsync(xc2L[0], 0, (size_t)BB * K2 * 2, stream);
        hipMemsetAsync(xc3H[0], 0, (size_t)BB * K2 * 2, stream);
        hipMemsetAsync(xc3L[0], 0, (size_t)BB * K2 * 2, stream);
    }

    for (int t = 0; t < TT; t++) {
        int cur = t & 1, nxt = cur ^ 1;
        // L1: z1 = [a3|h1|x_t] @ Wt1 -> gates -> h1; h1 bf16 -> xc2[cur] hprev, xc1[nxt] hself
        zg_v8<<<512, 256, 0, stream>>>(
            xc1H[cur], xc1L[cur], K1A, K1,
            xPH + (long)t * BB * K1X, xPL + (long)t * BB * K1X,
            WtH1, WtL1, b1, c1, h1,
            xc2H[cur], xc2L[cur], 0, K2,
            xc1H[nxt], xc1L[nxt], 256, K1A);
        qattn_v8<<<BB, 256, 0, stream>>>(h1, Wq, bq, keys,
            xc2H[cur], xc2L[cur], 512, K2,
            nullptr, nullptr, nullptr, 0);
        // L2
        zg_v8<<<512, 256, 0, stream>>>(
            xc2H[cur], xc2L[cur], K2, K2, nullptr, nullptr,
            WtH2, WtL2, b2, c2, h2,
            xc3H[cur], xc3L[cur], 0, K2,
            xc2H[nxt], xc2L[nxt], 768, K2);
        qattn_v8<<<BB, 256, 0, stream>>>(h2, Wq, bq, keys,
            xc3H[cur], xc3L[cur], 512, K2,
            nullptr, nullptr, nullptr, 0);
        // L3
        zg_v8<<<512, 256, 0, stream>>>(
            xc3H[cur], xc3L[cur], K2, K2, nullptr, nullptr,
            WtH3, WtL3, b3, c3, h3,
            nullptr, nullptr, 0, 0,
            xc3H[nxt], xc3L[nxt], 768, K2);
        qattn_v8<<<BB, 256, 0, stream>>>(h3, Wq, bq, keys,
            xc1H[nxt], xc1L[nxt], 0, K1A,
            Wo, bo, out, t);
    }
}

// Round 3
// 60729.413 us; speedup vs baseline: 1.7906x; 1.0078x over previous
//
#include <hip/hip_runtime.h>
#include <hip/hip_bf16.h>
#include <math.h>

#define BB 256
#define TT 256
#define VV 33
#define HH 512
#define DD 256
#define KKEY 512
#define G4 2048
#define K1 832     // GEMM-K layer1: [a 0:256 | h 256:768 | x 768:801 | pad 801:832]
#define K1A 768    // xcat1 row stride (a+h only)
#define K1X 64     // packed-x row stride (33 data + zero pad)
#define K2 1280    // [hprev 0:512 | a 512:768 | hself 768:1280]
#define CH 32      // attention keys chunk rows
#define KP 260     // klds row stride (fp32), 256 + 4 pad

typedef unsigned short u16;
typedef unsigned int u32;
typedef __attribute__((ext_vector_type(8))) short short8;
typedef __attribute__((ext_vector_type(4))) float float4v;

__device__ inline float bf2f(u16 v) {
    union { u32 u; float f; } c; c.u = ((u32)v) << 16; return c.f;
}
__device__ inline u16 f2bf(float f) {
    __hip_bfloat16 h = __float2bfloat16(f);
    union { __hip_bfloat16 h; u16 u; } c; c.h = h; return c.u;
}
__device__ inline void split_bf(float v, u16& hi, u16& lo) {
    hi = f2bf(v);
    lo = f2bf(v - bf2f(hi));
}

// ---------------- weight prep: Wt[col'][k], gate-interleaved columns ----------------
// col' = u*4 + g  <->  original col = g*512 + u
__global__ void prep_v7(const float* __restrict__ W, const float* __restrict__ U,
                        u16* __restrict__ WtH, u16* __restrict__ WtL, int Kd, int mode) {
    long idx = (long)blockIdx.x * blockDim.x + threadIdx.x;
    if (idx >= (long)G4 * Kd) return;
    int colp = (int)(idx / Kd);
    int k = (int)(idx % Kd);
    int col = (colp & 3) * 512 + (colp >> 2);
    float v = 0.f;
    if (mode == 1) {
        if (k < 256)      v = W[(long)(33 + k) * G4 + col];
        else if (k < 768) v = U[(long)(k - 256) * G4 + col];
        else if (k < 801) v = W[(long)(k - 768) * G4 + col];
    } else {
        if (k < 768) v = W[(long)k * G4 + col];
        else         v = U[(long)(k - 768) * G4 + col];
    }
    u16 hi, lo; split_bf(v, hi, lo);
    WtH[idx] = hi; WtL[idx] = lo;
}

// ---------------- Wq^T prep: WqT[d][j] = Wq[j][d], bf16 hi/lo ----------------
__global__ void prep_wq(const float* __restrict__ Wq,
                        u16* __restrict__ WqTH, u16* __restrict__ WqTL) {
    int idx = blockIdx.x * blockDim.x + threadIdx.x;
    if (idx >= DD * HH) return;
    int d = idx / HH, j = idx % HH;
    u16 hi, lo; split_bf(Wq[(long)j * DD + d], hi, lo);
    WqTH[idx] = hi; WqTL[idx] = lo;
}

// ---------------- pre-pack x for ALL t: xP[t][b][64] (33 data, rest zero) ----------------
__global__ void packx_v7(const float* __restrict__ x, u16* __restrict__ xPH, u16* __restrict__ xPL) {
    long idx = (long)blockIdx.x * blockDim.x + threadIdx.x;
    if (idx >= (long)TT * BB * K1X) return;
    int k = (int)(idx % K1X);
    long tb = idx / K1X;
    int b = (int)(tb % BB);
    int t = (int)(tb / BB);
    float v = (k < VV) ? x[((long)b * TT + t) * VV + k] : 0.f;
    u16 hi, lo; split_bf(v, hi, lo);
    xPH[idx] = hi; xPL[idx] = lo;
}

// ---------------- fused z-GEMM + LSTM gates; 32x32 tiles, grid 512, reg-prefetch ----------------
__global__ __launch_bounds__(256, 2) void zg_v9(
    const u16* __restrict__ aH, const u16* __restrict__ aL, int strideA, int Kd,
    const u16* __restrict__ xH, const u16* __restrict__ xL,   // layer1 x source (else null)
    const u16* __restrict__ wH, const u16* __restrict__ wL,
    const float* __restrict__ bias,
    float* __restrict__ c, float* __restrict__ h,
    u16* __restrict__ d0H, u16* __restrict__ d0L, int d0off, int d0stride,
    u16* __restrict__ d1H, u16* __restrict__ d1L, int d1off, int d1stride)
{
    __shared__ u16 AldsH[32 * 40];
    __shared__ u16 AldsL[32 * 40];
    __shared__ u16 WldsH[32 * 40];
    __shared__ u16 WldsL[32 * 40];
    __shared__ float zlds[32 * 36];

    int tid = threadIdx.x;
    int mt = blockIdx.x >> 6;    // 0..7
    int nt = blockIdx.x & 63;    // 0..63
    int M0 = mt * 32, N0 = nt * 32;

    int wave = tid >> 6, lane = tid & 63;
    int lr = lane & 15, lg = lane >> 4;
    int rbase = (wave & 1) * 16, cbase = (wave >> 1) * 16;

    int half = tid >> 7;
    int slot = tid & 127;
    int sr = slot >> 2, sp = slot & 3;

    const u16* aRow = (half ? aL : aH) + (long)(M0 + sr) * strideA;
    const u16* xRow = xH ? ((half ? xL : xH) + (long)(M0 + sr) * K1X) : nullptr;
    const u16* wRow = (half ? wL : wH) + (long)(N0 + sr) * Kd;
    u16* aDst = (half ? AldsL : AldsH) + sr * 40 + sp * 8;
    u16* wDst = (half ? WldsL : WldsH) + sr * 40 + sp * 8;

    auto loadA = [&](int kg) -> uint4 {
        return (xRow && kg >= K1A) ? *(const uint4*)(xRow + (kg - K1A))
                                   : *(const uint4*)(aRow + kg);
    };

    float4v acc = (float4v){0.f, 0.f, 0.f, 0.f};

    uint4 va = loadA(sp * 8);
    uint4 vw = *(const uint4*)(wRow + sp * 8);

    for (int k0 = 0; k0 < Kd; k0 += 32) {
        __syncthreads();
        *(uint4*)aDst = va;
        *(uint4*)wDst = vw;
        if (k0 + 32 < Kd) {
            int kg = k0 + 32 + sp * 8;
            va = loadA(kg);
            vw = *(const uint4*)(wRow + kg);
        }
        __syncthreads();
        // A fragment: m = rbase + (lane&15), k = (lane>>4)*8 + j   [m120-verified]
        short8 ah = *(const short8*)(&AldsH[(rbase + lr) * 40 + lg * 8]);
        short8 al = *(const short8*)(&AldsL[(rbase + lr) * 40 + lg * 8]);
        short8 bh = *(const short8*)(&WldsH[(cbase + lr) * 40 + lg * 8]);
        short8 bl = *(const short8*)(&WldsL[(cbase + lr) * 40 + lg * 8]);
        acc = __builtin_amdgcn_mfma_f32_16x16x32_bf16(ah, bh, acc, 0, 0, 0);
        acc = __builtin_amdgcn_mfma_f32_16x16x32_bf16(ah, bl, acc, 0, 0, 0);
        acc = __builtin_amdgcn_mfma_f32_16x16x32_bf16(al, bh, acc, 0, 0, 0);
    }

    // D: col = lane&15, row = (lane>>4)*4 + r   [m89-verified]
    #pragma unroll
    for (int r = 0; r < 4; r++)
        zlds[(rbase + lg * 4 + r) * 36 + cbase + lr] = acc[r];
    __syncthreads();

    // gates: 1 row x 1 unit per thread
    int um = tid & 7, ml = tid >> 3;       // um 0..7, ml 0..31
    int u = (nt << 3) + um;
    int m = M0 + ml;
    float zi  = zlds[ml * 36 + um * 4 + 0] + bias[u];
    float zf  = zlds[ml * 36 + um * 4 + 1] + bias[512 + u];
    float zg_ = zlds[ml * 36 + um * 4 + 2] + bias[1024 + u];
    float zo  = zlds[ml * 36 + um * 4 + 3] + bias[1536 + u];
    float i_ = 1.f / (1.f + expf(-zi));
    float f_ = 1.f / (1.f + expf(-zf));
    float g_ = tanhf(zg_);
    float o_ = 1.f / (1.f + expf(-zo));
    long idx = (long)m * HH + u;
    float cn = f_ * c[idx] + i_ * g_;
    c[idx] = cn;
    float hn = o_ * tanhf(cn);
    h[idx] = hn;
    u16 hi_, lo_; split_bf(hn, hi_, lo_);
    if (d0H) {
        d0H[(long)m * d0stride + d0off + u] = hi_;
        d0L[(long)m * d0stride + d0off + u] = lo_;
    }
    d1H[(long)m * d1stride + d1off + u] = hi_;
    d1L[(long)m * d1stride + d1off + u] = lo_;
}

// ---------------- q-GEMM: q[b][d] = h_bf16x3 @ WqT + bq; 32x32 tiles, grid 64 ----------------
__global__ __launch_bounds__(256) void qg_v9(
    const u16* __restrict__ aH, const u16* __restrict__ aL, int strideA,
    const u16* __restrict__ wH, const u16* __restrict__ wL,
    const float* __restrict__ bq, float* __restrict__ qout)
{
    __shared__ u16 AldsH[32 * 40];
    __shared__ u16 AldsL[32 * 40];
    __shared__ u16 WldsH[32 * 40];
    __shared__ u16 WldsL[32 * 40];

    int tid = threadIdx.x;
    int mt = blockIdx.x >> 3;    // 0..7
    int nt = blockIdx.x & 7;     // 0..7
    int M0 = mt * 32, N0 = nt * 32;

    int wave = tid >> 6, lane = tid & 63;
    int lr = lane & 15, lg = lane >> 4;
    int rbase = (wave & 1) * 16, cbase = (wave >> 1) * 16;

    int half = tid >> 7;
    int slot = tid & 127;
    int sr = slot >> 2, sp = slot & 3;

    const u16* aRow = (half ? aL : aH) + (long)(M0 + sr) * strideA;
    const u16* wRow = (half ? wL : wH) + (long)(N0 + sr) * HH;
    u16* aDst = (half ? AldsL : AldsH) + sr * 40 + sp * 8;
    u16* wDst = (half ? WldsL : WldsH) + sr * 40 + sp * 8;

    float4v acc = (float4v){0.f, 0.f, 0.f, 0.f};

    uint4 va = *(const uint4*)(aRow + sp * 8);
    uint4 vw = *(const uint4*)(wRow + sp * 8);

    for (int k0 = 0; k0 < HH; k0 += 32) {
        __syncthreads();
        *(uint4*)aDst = va;
        *(uint4*)wDst = vw;
        if (k0 + 32 < HH) {
            int kg = k0 + 32 + sp * 8;
            va = *(const uint4*)(aRow + kg);
            vw = *(const uint4*)(wRow + kg);
        }
        __syncthreads();
        short8 ah = *(const short8*)(&AldsH[(rbase + lr) * 40 + lg * 8]);
        short8 al = *(const short8*)(&AldsL[(rbase + lr) * 40 + lg * 8]);
        short8 bh = *(const short8*)(&WldsH[(cbase + lr) * 40 + lg * 8]);
        short8 bl = *(const short8*)(&WldsL[(cbase + lr) * 40 + lg * 8]);
        acc = __builtin_amdgcn_mfma_f32_16x16x32_bf16(ah, bh, acc, 0, 0, 0);
        acc = __builtin_amdgcn_mfma_f32_16x16x32_bf16(ah, bl, acc, 0, 0, 0);
        acc = __builtin_amdgcn_mfma_f32_16x16x32_bf16(al, bh, acc, 0, 0, 0);
    }

    #pragma unroll
    for (int r = 0; r < 4; r++) {
        int m = M0 + rbase + lg * 4 + r;
        int col = N0 + cbase + lr;
        qout[(long)m * DD + col] = acc[r] + bq[col];
    }
}

// ---------------- single-pass attention (no max bookkeeping) + layer3 output proj ----------------
__global__ __launch_bounds__(256) void attn_v9(
    const float* __restrict__ qv, const float* __restrict__ keys,
    u16* __restrict__ dH, u16* __restrict__ dL, int doff, int dstride,
    const float* __restrict__ h,
    const float* __restrict__ Wo, const float* __restrict__ bo,
    float* __restrict__ out, int t)
{
    __shared__ __align__(16) float klds[CH * KP];
    __shared__ __align__(16) float plds[CH];
    __shared__ __align__(16) float hlds[HH];
    __shared__ __align__(16) float alds[DD];

    int b = blockIdx.x, tid = threadIdx.x;
    int lane = tid & 63, wave = tid >> 6;

    const float* kb = keys + (long)b * KKEY * DD;
    float4 q4 = *(const float4*)(qv + (long)b * DD + lane * 4);

    float l_run = 0.f, acc = 0.f;

    // prefetch chunk 0: thread covers rows wave+4i, dims lane*4..+4
    float4 kv[8];
    #pragma unroll
    for (int i = 0; i < 8; i++)
        kv[i] = *(const float4*)(kb + (long)(wave + 4 * i) * DD + lane * 4);

    for (int k0 = 0; k0 < KKEY; k0 += CH) {
        __syncthreads();   // klds/plds WAR vs previous accumulation
        float pp[8];
        #pragma unroll
        for (int i = 0; i < 8; i++) {
            *(float4*)(&klds[(wave + 4 * i) * KP + lane * 4]) = kv[i];
            pp[i] = kv[i].x * q4.x + kv[i].y * q4.y + kv[i].z * q4.z + kv[i].w * q4.w;
        }
        // prefetch next chunk (overlaps with reduce + accumulate)
        float4 kn[8];
        if (k0 + CH < KKEY) {
            #pragma unroll
            for (int i = 0; i < 8; i++)
                kn[i] = *(const float4*)(kb + (long)(k0 + CH + wave + 4 * i) * DD + lane * 4);
        }
        // wave-wide reduce of partial dots -> p = exp(score)
        #pragma unroll
        for (int i = 0; i < 8; i++) {
            float s = pp[i];
            s += __shfl_xor(s, 32); s += __shfl_xor(s, 16); s += __shfl_xor(s, 8);
            s += __shfl_xor(s, 4);  s += __shfl_xor(s, 2);  s += __shfl_xor(s, 1);
            if (lane == i) plds[wave + 4 * i] = expf(s);
        }
        __syncthreads();
        // weighted accumulation: thread owns dim d = tid
        float a0 = 0.f, a1 = 0.f;
        #pragma unroll
        for (int k = 0; k < CH; k += 4) {
            float4 p4 = *(const float4*)(&plds[k]);
            l_run += (p4.x + p4.y) + (p4.z + p4.w);
            a0 += p4.x * klds[(k + 0) * KP + tid] + p4.z * klds[(k + 2) * KP + tid];
            a1 += p4.y * klds[(k + 1) * KP + tid] + p4.w * klds[(k + 3) * KP + tid];
        }
        acc += a0 + a1;
        #pragma unroll
        for (int i = 0; i < 8; i++) kv[i] = kn[i];
    }

    float av = acc / l_run;
    u16 hi_, lo_; split_bf(av, hi_, lo_);
    dH[(long)b * dstride + doff + tid] = hi_;
    dL[(long)b * dstride + doff + tid] = lo_;

    if (Wo) {
        alds[tid] = av;
        hlds[tid]       = h[(long)b * HH + tid];
        hlds[tid + 256] = h[(long)b * HH + 256 + tid];
        __syncthreads();
        for (int v = wave; v < VV; v += 4) {
            float s = 0.f;
            for (int i = lane; i < HH; i += 64) s += hlds[i] * Wo[(long)i * VV + v];
            for (int i = lane; i < DD; i += 64) s += alds[i] * Wo[(long)(HH + i) * VV + v];
            for (int o = 32; o > 0; o >>= 1) s += __shfl_xor(s, o);
            if (lane == 0) out[((long)b * TT + t) * VV + v] = s + bo[v];
        }
    }
}

// ---------------- launch ----------------

extern "C" void kernel_launch(void* const* d_in, const int* in_sizes, int n_in,
                              void* d_out, int out_size, void* d_ws, size_t ws_size,
                              hipStream_t stream) {
    const float *x = nullptr, *keys = nullptr, *W1 = nullptr, *U1 = nullptr,
                *b1 = nullptr, *W2 = nullptr, *U2 = nullptr, *b2 = nullptr,
                *W3 = nullptr, *U3 = nullptr, *b3 = nullptr, *Wq = nullptr,
                *bq = nullptr, *Wo = nullptr, *bo = nullptr;
    {
        int cW23 = 0, cU = 0, cb = 0;
        for (int i = 0; i < n_in; i++) {
            const float* q = (const float*)d_in[i];
            switch (in_sizes[i]) {
                case 2162688:  x = q; break;
                case 33554432: keys = q; break;
                case 591872:   W1 = q; break;
                case 1572864:  if (cW23 == 0) W2 = q; else W3 = q; cW23++; break;
                case 1048576:  if (cU == 0) U1 = q; else if (cU == 1) U2 = q; else U3 = q; cU++; break;
                case 2048:     if (cb == 0) b1 = q; else if (cb == 1) b2 = q; else b3 = q; cb++; break;
                case 131072:   Wq = q; break;
                case 256:      bq = q; break;
                case 25344:    Wo = q; break;
                case 33:       bo = q; break;
                default: break;
            }
        }
    }
    float* out = (float*)d_out;

    char* p = (char*)d_ws;
    auto alloc = [&](size_t n) { char* r = p; p += (n + 255) & ~(size_t)255; return r; };
    u16* WtH1 = (u16*)alloc((size_t)G4 * K1 * 2);
    u16* WtL1 = (u16*)alloc((size_t)G4 * K1 * 2);
    u16* WtH2 = (u16*)alloc((size_t)G4 * K2 * 2);
    u16* WtL2 = (u16*)alloc((size_t)G4 * K2 * 2);
    u16* WtH3 = (u16*)alloc((size_t)G4 * K2 * 2);
    u16* WtL3 = (u16*)alloc((size_t)G4 * K2 * 2);
    u16* WqTH = (u16*)alloc((size_t)DD * HH * 2);
    u16* WqTL = (u16*)alloc((size_t)DD * HH * 2);
    u16* xPH = (u16*)alloc((size_t)TT * BB * K1X * 2);
    u16* xPL = (u16*)alloc((size_t)TT * BB * K1X * 2);
    u16* xc1H[2]; u16* xc1L[2]; u16* xc2H[2]; u16* xc2L[2]; u16* xc3H[2]; u16* xc3L[2];
    for (int i = 0; i < 2; i++) {
        xc1H[i] = (u16*)alloc((size_t)BB * K1A * 2);
        xc1L[i] = (u16*)alloc((size_t)BB * K1A * 2);
        xc2H[i] = (u16*)alloc((size_t)BB * K2 * 2);
        xc2L[i] = (u16*)alloc((size_t)BB * K2 * 2);
        xc3H[i] = (u16*)alloc((size_t)BB * K2 * 2);
        xc3L[i] = (u16*)alloc((size_t)BB * K2 * 2);
    }
    float* h1 = (float*)alloc((size_t)BB * HH * 4);
    float* c1 = (float*)alloc((size_t)BB * HH * 4);
    float* h2 = (float*)alloc((size_t)BB * HH * 4);
    float* c2 = (float*)alloc((size_t)BB * HH * 4);
    float* h3 = (float*)alloc((size_t)BB * HH * 4);
    float* c3 = (float*)alloc((size_t)BB * HH * 4);
    float* qv = (float*)alloc((size_t)BB * DD * 4);

    {
        long t1 = (long)G4 * K1;
        prep_v7<<<(int)((t1 + 255) / 256), 256, 0, stream>>>(W1, U1, WtH1, WtL1, K1, 1);
        long t2 = (long)G4 * K2;
        prep_v7<<<(int)((t2 + 255) / 256), 256, 0, stream>>>(W2, U2, WtH2, WtL2, K2, 2);
        prep_v7<<<(int)((t2 + 255) / 256), 256, 0, stream>>>(W3, U3, WtH3, WtL3, K2, 2);
        prep_wq<<<(DD * HH + 255) / 256, 256, 0, stream>>>(Wq, WqTH, WqTL);
        long tx = (long)TT * BB * K1X;
        packx_v7<<<(int)((tx + 255) / 256), 256, 0, stream>>>(x, xPH, xPL);
        hipMemsetAsync(c1, 0, (size_t)BB * HH * 4, stream);
        hipMemsetAsync(c2, 0, (size_t)BB * HH * 4, stream);
        hipMemsetAsync(c3, 0, (size_t)BB * HH * 4, stream);
        hipMemsetAsync(xc1H[0], 0, (size_t)BB * K1A * 2, stream);
        hipMemsetAsync(xc1L[0], 0, (size_t)BB * K1A * 2, stream);
        hipMemsetAsync(xc2H[0], 0, (size_t)BB * K2 * 2, stream);
        hipMemsetAsync(xc2L[0], 0, (size_t)BB * K2 * 2, stream);
        hipMemsetAsync(xc3H[0], 0, (size_t)BB * K2 * 2, stream);
        hipMemsetAsync(xc3L[0], 0, (size_t)BB * K2 * 2, stream);
    }

    for (int t = 0; t < TT; t++) {
        int cur = t & 1, nxt = cur ^ 1;
        // L1: z1 = [a3|h1|x_t] @ Wt1 -> gates -> h1 (bf16 to xc2[cur].hprev, xc1[nxt].hself)
        zg_v9<<<512, 256, 0, stream>>>(
            xc1H[cur], xc1L[cur], K1A, K1,
            xPH + (long)t * BB * K1X, xPL + (long)t * BB * K1X,
            WtH1, WtL1, b1, c1, h1,
            xc2H[cur], xc2L[cur], 0, K2,
            xc1H[nxt], xc1L[nxt], 256, K1A);
        // q1 = h1 @ Wq + bq  (reads h1 hi/lo from xc2[cur] offset 0)
        qg_v9<<<64, 256, 0, stream>>>(
            xc2H[cur], xc2L[cur], K2, WqTH, WqTL, bq, qv);
        // a1 -> xc2[cur].a
        attn_v9<<<BB, 256, 0, stream>>>(qv, keys,
            xc2H[cur], xc2L[cur], 512, K2,
            h1, nullptr, nullptr, nullptr, 0);
        // L2
        zg_v9<<<512, 256, 0, stream>>>(
            xc2H[cur], xc2L[cur], K2, K2, nullptr, nullptr,
            WtH2, WtL2, b2, c2, h2,
            xc3H[cur], xc3L[cur], 0, K2,
            xc2H[nxt], xc2L[nxt], 768, K2);
        qg_v9<<<64, 256, 0, stream>>>(
            xc3H[cur], xc3L[cur], K2, WqTH, WqTL, bq, qv);
        attn_v9<<<BB, 256, 0, stream>>>(qv, keys,
            xc3H[cur], xc3L[cur], 512, K2,
            h2, nullptr, nullptr, nullptr, 0);
        // L3
        zg_v9<<<512, 256, 0, stream>>>(
            xc3H[cur], xc3L[cur], K2, K2, nullptr, nullptr,
            WtH3, WtL3, b3, c3, h3,
            nullptr, nullptr, 0, 0,
            xc3H[nxt], xc3L[nxt], 768, K2);
        // q3 reads h3 hi/lo from xc3[nxt] offset 768
        qg_v9<<<64, 256, 0, stream>>>(
            xc3H[nxt] + 768, xc3L[nxt] + 768, K2, WqTH, WqTL, bq, qv);
        // a3 -> xc1[nxt].a ; fused output projection
        attn_v9<<<BB, 256, 0, stream>>>(qv, keys,
            xc1H[nxt], xc1L[nxt], 0, K1A,
            h3, Wo, bo, out, t);
    }
}